// Round 8
// baseline (3156.710 us; speedup 1.0000x reference)
//
#include <hip/hip_runtime.h>
#include <hip/hip_bf16.h>
#include <math.h>

// Problem constants
#define BB   4
#define SSQ  1024
#define DDM  512
#define HHD  8
#define KTOP 204
#define NPAT 8
#define PDIM 64

typedef unsigned long long u64;
typedef unsigned int u32;
typedef unsigned short u16;

// Polymorphic input loader: flag==1 -> f32 data, flag==0 -> bf16 data.
__device__ __forceinline__ float ldin(const void* p, size_t i, int f32) {
    if (f32) return ((const float*)p)[i];
    u16 h = ((const u16*)p)[i];
    return __uint_as_float(((u32)h) << 16);
}

// ---------------------------------------------------------------------------
// K0: input dtype detection (sample low-half u16s of `query`).
// ---------------------------------------------------------------------------
__global__ void detect_kernel(const void* q, int* flag) {
    if (threadIdx.x == 0 && blockIdx.x == 0) {
        const u16* p = (const u16*)q;
        int good = 0;
        for (int i = 0; i < 512; i += 2) {
            float v = __uint_as_float(((u32)p[i]) << 16);
            float a = fabsf(v);
            if (a > 0.00390625f && a < 64.f) ++good;
        }
        *flag = (good < 128) ? 1 : 0;   // few plausible bf16 values -> data is f32
    }
}

// ---------------------------------------------------------------------------
// K1: pattern learner -> weighted_patterns (out2, f32). One block per row.
// ---------------------------------------------------------------------------
__global__ __launch_bounds__(64)
void pattern_kernel(const void* __restrict__ q,
                    const void* __restrict__ pw1, const void* __restrict__ pb1,
                    const void* __restrict__ pw2, const void* __restrict__ pb2,
                    const void* __restrict__ bank, const void* __restrict__ gate,
                    const int* __restrict__ flagp,
                    float* __restrict__ out2) {
    __shared__ float qs[DDM];
    __shared__ float h1[PDIM];
    __shared__ float enc[PDIM];
    __shared__ float ps[NPAT];
    int f32 = *flagp;
    int row = blockIdx.x;
    int t = threadIdx.x;
    for (int i = t; i < DDM; i += 64) qs[i] = ldin(q, (size_t)row * DDM + i, f32);
    __syncthreads();
    float acc = ldin(pb1, t, f32);
    for (int d = 0; d < DDM; ++d) acc = fmaf(qs[d], ldin(pw1, (size_t)d * PDIM + t, f32), acc);
    h1[t] = fmaxf(acc, 0.f);
    __syncthreads();
    float acc2 = ldin(pb2, t, f32);
    for (int d = 0; d < PDIM; ++d) acc2 = fmaf(h1[d], ldin(pw2, (size_t)d * PDIM + t, f32), acc2);
    enc[t] = tanhf(acc2);
    __syncthreads();
    if (t < NPAT) {
        float a = 0.f;
        for (int d = 0; d < PDIM; ++d) a = fmaf(enc[d], ldin(bank, (size_t)t * PDIM + d, f32), a);
        ps[t] = a * 0.125f;
    }
    __syncthreads();
    if (t < NPAT) {
        float m = ps[0];
        for (int n = 1; n < NPAT; ++n) m = fmaxf(m, ps[n]);
        float sum = 0.f;
        for (int n = 0; n < NPAT; ++n) sum += expf(ps[n] - m);
        float e = expf(ps[t] - m);
        out2[(size_t)row * NPAT + t] = e / sum * ldin(gate, t, f32);
    }
}

// ---------------------------------------------------------------------------
// K2: f32 projection (z=0:Q, 1:K, 2:V), all batches. Each output element is
// ONE sequential f32 FMA chain over d=0..511 (ascending) + bias — mimicking
// Eigen/XLA-CPU gemm accumulation so the mask top-k decisions match the ref.
// ---------------------------------------------------------------------------
__global__ __launch_bounds__(256)
void projf_kernel(const void* __restrict__ query, const void* __restrict__ key,
                  const void* __restrict__ value,
                  const void* __restrict__ wq, const void* __restrict__ bq,
                  const void* __restrict__ wk, const void* __restrict__ bk,
                  const void* __restrict__ wv, const void* __restrict__ bv,
                  const int* __restrict__ flagp,
                  float* __restrict__ Qf32, float* __restrict__ Kf32, float* __restrict__ Vf32) {
    __shared__ float Xs[64][65];
    __shared__ float Ws[64][65];
    int f32 = *flagp;
    int z = blockIdx.z;
    const void* X = (z == 0) ? query : ((z == 1) ? key : value);
    const void* W = (z == 0) ? wq : ((z == 1) ? wk : wv);
    const void* Bv = (z == 0) ? bq : ((z == 1) ? bk : bv);
    float* Y = (z == 0) ? Qf32 : ((z == 1) ? Kf32 : Vf32);
    int c0 = blockIdx.x * 64, r0 = blockIdx.y * 64;
    int tx = threadIdx.x & 15, ty = threadIdx.x >> 4;
    float acc[4][4] = {};
    for (int k0 = 0; k0 < DDM; k0 += 64) {
        for (int idx = threadIdx.x; idx < 64 * 64; idx += 256) {
            int r = idx >> 6, kk = idx & 63;
            Xs[r][kk] = ldin(X, (size_t)(r0 + r) * DDM + k0 + kk, f32);
            Ws[r][kk] = ldin(W, (size_t)(k0 + r) * DDM + c0 + kk, f32);
        }
        __syncthreads();
        for (int kk = 0; kk < 64; ++kk) {           // ascending k: exact chain
            float xv[4], wv[4];
            #pragma unroll
            for (int a = 0; a < 4; ++a) xv[a] = Xs[ty + 16 * a][kk];
            #pragma unroll
            for (int b2 = 0; b2 < 4; ++b2) wv[b2] = Ws[kk][tx + 16 * b2];
            #pragma unroll
            for (int a = 0; a < 4; ++a)
                #pragma unroll
                for (int b2 = 0; b2 < 4; ++b2)
                    acc[a][b2] = fmaf(xv[a], wv[b2], acc[a][b2]);
        }
        __syncthreads();
    }
    #pragma unroll
    for (int a = 0; a < 4; ++a) {
        int r = r0 + ty + 16 * a;
        #pragma unroll
        for (int b2 = 0; b2 < 4; ++b2) {
            int c = c0 + tx + 16 * b2;
            Y[(size_t)r * DDM + c] = acc[a][b2] + ldin(Bv, c, f32);
        }
    }
}

// ---------------------------------------------------------------------------
// K3: per-batch f32 scores  S3[i,j] = fma-chain_d(Qf[i,d]*Kf[j,d]) * 0.125
// Same sequential-chain semantics (ascending d, f32 FMA, then exact /8).
// ---------------------------------------------------------------------------
__global__ __launch_bounds__(256)
void scoresf_kernel(const float* __restrict__ Qb, const float* __restrict__ Kb,
                    float* __restrict__ S3) {
    __shared__ float Qs[64][65];
    __shared__ float Ks[64][65];
    int j0 = blockIdx.x * 64, i0 = blockIdx.y * 64;
    int tx = threadIdx.x & 15, ty = threadIdx.x >> 4;
    float acc[4][4] = {};
    for (int k0 = 0; k0 < DDM; k0 += 64) {
        for (int idx = threadIdx.x; idx < 64 * 64; idx += 256) {
            int r = idx >> 6, kk = idx & 63;
            Qs[r][kk] = Qb[(size_t)(i0 + r) * DDM + k0 + kk];
            Ks[r][kk] = Kb[(size_t)(j0 + r) * DDM + k0 + kk];
        }
        __syncthreads();
        for (int kk = 0; kk < 64; ++kk) {           // ascending d: exact chain
            float qv[4], kv[4];
            #pragma unroll
            for (int a = 0; a < 4; ++a) qv[a] = Qs[ty + 16 * a][kk];
            #pragma unroll
            for (int b2 = 0; b2 < 4; ++b2) kv[b2] = Ks[tx + 16 * b2][kk];
            #pragma unroll
            for (int a = 0; a < 4; ++a)
                #pragma unroll
                for (int b2 = 0; b2 < 4; ++b2)
                    acc[a][b2] = fmaf(qv[a], kv[b2], acc[a][b2]);
        }
        __syncthreads();
    }
    #pragma unroll
    for (int a = 0; a < 4; ++a)
        #pragma unroll
        for (int b2 = 0; b2 < 4; ++b2)
            S3[(size_t)(i0 + ty + 16 * a) * SSQ + (j0 + tx + 16 * b2)] = acc[a][b2] * 0.125f;
}

// ---------------------------------------------------------------------------
// K4: per-row top-204 by 204 argmax iterations on the f32 scores
// (value desc, tie -> lowest index; set semantics match jax top_k scatter).
// ---------------------------------------------------------------------------
__global__ __launch_bounds__(256)
void maskselect_kernel(const float* __restrict__ S3b,
                       u64* __restrict__ bitmask,   // (B*S, 16)
                       int b) {
    __shared__ float vals[1024];
    __shared__ u32 selv[1024];
    __shared__ float rv[4];
    __shared__ int ri[4];
    int i = blockIdx.x;
    int t = threadIdx.x;
    int lane = t & 63, w = t >> 6;
    const float* srow = S3b + (size_t)i * SSQ;
    for (int j = t; j < 1024; j += 256) { vals[j] = srow[j]; selv[j] = 0u; }
    __syncthreads();
    for (int it = 0; it < KTOP; ++it) {
        float bv = -3.4e38f; int bi = 1024;
        #pragma unroll
        for (int a = 0; a < 4; ++a) {
            int j = t + 256 * a;
            if (!selv[j]) {
                float v = vals[j];
                if (v > bv || (v == bv && j < bi)) { bv = v; bi = j; }
            }
        }
        #pragma unroll
        for (int off = 32; off >= 1; off >>= 1) {
            float ov = __shfl_xor(bv, off);
            int oi = __shfl_xor(bi, off);
            if (ov > bv || (ov == bv && oi < bi)) { bv = ov; bi = oi; }
        }
        if (lane == 0) { rv[w] = bv; ri[w] = bi; }
        __syncthreads();
        if (t == 0) {
            float fv = rv[0]; int fi = ri[0];
            for (int q = 1; q < 4; ++q)
                if (rv[q] > fv || (rv[q] == fv && ri[q] < fi)) { fv = rv[q]; fi = ri[q]; }
            if (fi < 1024) selv[fi] = 1u;
        }
        __syncthreads();
    }
    if (t < 16) {
        u64 wbits = 0;
        for (int l = 0; l < 64; ++l)
            if (selv[t * 64 + l]) wbits |= (1ull << l);
        bitmask[((size_t)b * SSQ + i) * 16 + t] = wbits;
    }
}

// ---------------------------------------------------------------------------
// K5: dense masked attention driven by the bitmask (loose tolerance path).
// ---------------------------------------------------------------------------
__global__ __launch_bounds__(256)
void attn_dense_kernel(const float* __restrict__ Qf32, const float* __restrict__ Kf32,
                       const float* __restrict__ Vf32, const u64* __restrict__ bitmask,
                       float* __restrict__ AO) {
    __shared__ float qs[4][64];
    __shared__ float pb[4][1024];
    int lane = threadIdx.x & 63, w = threadIdx.x >> 6;
    int b = blockIdx.z, h = blockIdx.y, i = blockIdx.x * 4 + w;
    size_t qoff = ((size_t)(b * SSQ + i)) * DDM + h * 64;
    qs[w][lane] = Qf32[qoff + lane];
    const u64* mb = bitmask + ((size_t)(b * SSQ + i)) * 16;
    float m = -1e30f;
    for (int c = 0; c < 16; ++c) {
        int j = c * 64 + lane;
        u64 wbits = mb[c];
        const float* kr = Kf32 + ((size_t)(b * SSQ + j)) * DDM + h * 64;
        float s = 0.f;
        #pragma unroll
        for (int d = 0; d < 64; d += 4) {
            float4 kv = *reinterpret_cast<const float4*>(kr + d);
            s += qs[w][d] * kv.x + qs[w][d + 1] * kv.y +
                 qs[w][d + 2] * kv.z + qs[w][d + 3] * kv.w;
        }
        s *= 0.125f;
        if (!((wbits >> lane) & 1ull)) s = -1e9f;
        pb[w][j] = s;
        m = fmaxf(m, s);
    }
    #pragma unroll
    for (int off = 32; off >= 1; off >>= 1) m = fmaxf(m, __shfl_xor(m, off));
    float lsum = 0.f;
    for (int c = 0; c < 16; ++c) {
        int j = c * 64 + lane;
        float p = expf(pb[w][j] - m);   // masked: exp(-1e9 - m) == 0 exactly
        pb[w][j] = p;
        lsum += p;
    }
    #pragma unroll
    for (int off = 32; off >= 1; off >>= 1) lsum += __shfl_xor(lsum, off);
    float acc = 0.f;
    const float* Vb = Vf32 + ((size_t)b * SSQ) * DDM + h * 64 + lane;
    for (int j = 0; j < 1024; ++j) acc = fmaf(pb[w][j], Vb[(size_t)j * DDM], acc);
    AO[qoff + lane] = acc / lsum;
}

// ---------------------------------------------------------------------------
// K6: output projection  out0 = AO @ wo + bo  (f32 out)
// ---------------------------------------------------------------------------
__global__ __launch_bounds__(256)
void outproj_kernel(const float* __restrict__ AO, const void* __restrict__ wo,
                    const void* __restrict__ bo, const int* __restrict__ flagp,
                    float* __restrict__ out0) {
    __shared__ float Xs[64][65];
    __shared__ float Ws[64][65];
    int f32 = *flagp;
    int c0 = blockIdx.x * 64, r0 = blockIdx.y * 64;
    int tx = threadIdx.x & 15, ty = threadIdx.x >> 4;
    float acc[4][4] = {};
    for (int k0 = 0; k0 < DDM; k0 += 64) {
        for (int idx = threadIdx.x; idx < 64 * 64; idx += 256) {
            int r = idx >> 6, kk = idx & 63;
            Xs[r][kk] = AO[(size_t)(r0 + r) * DDM + k0 + kk];
            Ws[r][kk] = ldin(wo, (size_t)(k0 + r) * DDM + c0 + kk, f32);
        }
        __syncthreads();
        for (int kk = 0; kk < 64; ++kk) {
            float xv[4], wv[4];
            #pragma unroll
            for (int a = 0; a < 4; ++a) xv[a] = Xs[ty + 16 * a][kk];
            #pragma unroll
            for (int b2 = 0; b2 < 4; ++b2) wv[b2] = Ws[kk][tx + 16 * b2];
            #pragma unroll
            for (int a = 0; a < 4; ++a)
                #pragma unroll
                for (int b2 = 0; b2 < 4; ++b2)
                    acc[a][b2] = fmaf(xv[a], wv[b2], acc[a][b2]);
        }
        __syncthreads();
    }
    #pragma unroll
    for (int a = 0; a < 4; ++a) {
        int r = r0 + ty + 16 * a;
        #pragma unroll
        for (int b2 = 0; b2 < 4; ++b2) {
            int c = c0 + tx + 16 * b2;
            out0[(size_t)r * DDM + c] = acc[a][b2] + ldin(bo, c, f32);
        }
    }
}

// ---------------------------------------------------------------------------
// K7 (last): expand bitmask -> f32 mask for all 8 heads, overwriting ALL of
// out1 (which served as scratch until now). One block per (b,i) row.
// ---------------------------------------------------------------------------
__global__ __launch_bounds__(256)
void maskwrite_kernel(const u64* __restrict__ bitmask,
                      float* __restrict__ out1) {
    int row = blockIdx.x;            // b*S + i
    int t = threadIdx.x;
    int b = row >> 10, i = row & 1023;
    const u64* mb = bitmask + (size_t)row * 16;
    int j0 = t * 4;
    u64 w0 = mb[j0 >> 6];
    float4 v4;
    v4.x = ((w0 >> (j0 & 63)) & 1ull) ? 1.0f : 0.0f;
    v4.y = ((w0 >> ((j0 + 1) & 63)) & 1ull) ? 1.0f : 0.0f;
    v4.z = ((w0 >> ((j0 + 2) & 63)) & 1ull) ? 1.0f : 0.0f;
    v4.w = ((w0 >> ((j0 + 3) & 63)) & 1ull) ? 1.0f : 0.0f;
    for (int h = 0; h < HHD; ++h) {
        size_t base_o = (((size_t)b * HHD + h) * SSQ + i) * SSQ;
        *reinterpret_cast<float4*>(out1 + base_o + (size_t)t * 4) = v4;
    }
}

// ---------------------------------------------------------------------------
extern "C" void kernel_launch(void* const* d_in, const int* in_sizes, int n_in,
                              void* d_out, int out_size, void* d_ws, size_t ws_size,
                              hipStream_t stream) {
    const void* query = d_in[0];
    const void* key   = d_in[1];
    const void* value = d_in[2];
    const void* wq = d_in[3];  const void* bq = d_in[4];
    const void* wk = d_in[5];  const void* bk = d_in[6];
    const void* wv = d_in[7];  const void* bv = d_in[8];
    const void* wo = d_in[9];  const void* bo = d_in[10];
    const void* pw1 = d_in[11]; const void* pb1 = d_in[12];
    const void* pw2 = d_in[13]; const void* pb2 = d_in[14];
    const void* pattern_bank = d_in[15];
    const void* pattern_gate = d_in[16];

    // Outputs are FLOAT32 (confirmed: out0 passed in round 7).
    float* out0 = (float*)d_out;                          // (B,S,D)   2M f32
    float* out1 = out0 + (size_t)BB * SSQ * DDM;          // (B,H,S,S) 33.5M f32 (134MB)
    float* out2 = out1 + (size_t)BB * HHD * SSQ * SSQ;    // (B,S,NP)  32K f32

    // d_ws: tiny header only (dtype flag + 512KB bitmask).
    int* flag = (int*)d_ws;
    u64* bitmask = (u64*)((char*)d_ws + 65536);           // (B*S,16) = 512KB

    // All large scratch lives INSIDE out1's 134MB, overwritten by maskwrite.
    char* SCR = (char*)out1;
    float* Qf32 = (float*)(SCR);                          // [0,8M)
    float* Kf32 = (float*)(SCR + (8ull << 20));           // [8M,16M)
    float* Vf32 = (float*)(SCR + (16ull << 20));          // [16M,24M)
    float* AO   = (float*)(SCR + (24ull << 20));          // [24M,32M)
    float* S3f  = (float*)(SCR + (32ull << 20));          // [32M,36M) per-batch scores

    detect_kernel<<<dim3(1), dim3(64), 0, stream>>>(query, flag);

    pattern_kernel<<<dim3(BB * SSQ), dim3(64), 0, stream>>>(
        query, pw1, pb1, pw2, pb2, pattern_bank, pattern_gate, flag, out2);

    // f32 Q/K/V projections (exact sequential-FMA-chain semantics)
    projf_kernel<<<dim3(DDM / 64, BB * SSQ / 64, 3), dim3(256), 0, stream>>>(
        query, key, value, wq, bq, wk, bk, wv, bv, flag, Qf32, Kf32, Vf32);

    // f32 mask pipeline, one batch at a time
    for (int b = 0; b < BB; ++b) {
        const float* Qb = Qf32 + (size_t)b * SSQ * DDM;
        const float* Kb = Kf32 + (size_t)b * SSQ * DDM;
        scoresf_kernel<<<dim3(SSQ / 64, SSQ / 64), dim3(256), 0, stream>>>(Qb, Kb, S3f);
        maskselect_kernel<<<dim3(SSQ), dim3(256), 0, stream>>>(S3f, bitmask, b);
    }

    attn_dense_kernel<<<dim3(SSQ / 4, HHD, BB), dim3(256), 0, stream>>>(
        Qf32, Kf32, Vf32, bitmask, AO);

    outproj_kernel<<<dim3(DDM / 64, BB * SSQ / 64), dim3(256), 0, stream>>>(
        AO, wo, bo, flag, out0);

    // LAST: expand bitmask into out1 (f32 mask), erasing all scratch
    maskwrite_kernel<<<dim3(BB * SSQ), dim3(256), 0, stream>>>(bitmask, out1);
}

// Round 9
// 1006.964 us; speedup vs baseline: 3.1349x; 3.1349x over previous
//
#include <hip/hip_runtime.h>
#include <hip/hip_bf16.h>
#include <math.h>

// Problem constants
#define BB   4
#define SSQ  1024
#define DDM  512
#define HHD  8
#define KTOP 204
#define NPAT 8
#define PDIM 64

typedef unsigned long long u64;
typedef unsigned int u32;
typedef unsigned short u16;

// Polymorphic input loader: flag==1 -> f32 data, flag==0 -> bf16 data.
__device__ __forceinline__ float ldin(const void* p, size_t i, int f32) {
    if (f32) return ((const float*)p)[i];
    u16 h = ((const u16*)p)[i];
    return __uint_as_float(((u32)h) << 16);
}

// ---------------------------------------------------------------------------
// K0: input dtype detection (sample low-half u16s of `query`).
// ---------------------------------------------------------------------------
__global__ void detect_kernel(const void* q, int* flag) {
    if (threadIdx.x == 0 && blockIdx.x == 0) {
        const u16* p = (const u16*)q;
        int good = 0;
        for (int i = 0; i < 512; i += 2) {
            float v = __uint_as_float(((u32)p[i]) << 16);
            float a = fabsf(v);
            if (a > 0.00390625f && a < 64.f) ++good;
        }
        *flag = (good < 128) ? 1 : 0;   // few plausible bf16 values -> data is f32
    }
}

// ---------------------------------------------------------------------------
// K1: pattern learner -> weighted_patterns (out2, f32). One block per row.
// ---------------------------------------------------------------------------
__global__ __launch_bounds__(64)
void pattern_kernel(const void* __restrict__ q,
                    const void* __restrict__ pw1, const void* __restrict__ pb1,
                    const void* __restrict__ pw2, const void* __restrict__ pb2,
                    const void* __restrict__ bank, const void* __restrict__ gate,
                    const int* __restrict__ flagp,
                    float* __restrict__ out2) {
    __shared__ float qs[DDM];
    __shared__ float h1[PDIM];
    __shared__ float enc[PDIM];
    __shared__ float ps[NPAT];
    int f32 = *flagp;
    int row = blockIdx.x;
    int t = threadIdx.x;
    for (int i = t; i < DDM; i += 64) qs[i] = ldin(q, (size_t)row * DDM + i, f32);
    __syncthreads();
    float acc = ldin(pb1, t, f32);
    for (int d = 0; d < DDM; ++d) acc = fmaf(qs[d], ldin(pw1, (size_t)d * PDIM + t, f32), acc);
    h1[t] = fmaxf(acc, 0.f);
    __syncthreads();
    float acc2 = ldin(pb2, t, f32);
    for (int d = 0; d < PDIM; ++d) acc2 = fmaf(h1[d], ldin(pw2, (size_t)d * PDIM + t, f32), acc2);
    enc[t] = tanhf(acc2);
    __syncthreads();
    if (t < NPAT) {
        float a = 0.f;
        for (int d = 0; d < PDIM; ++d) a = fmaf(enc[d], ldin(bank, (size_t)t * PDIM + d, f32), a);
        ps[t] = a * 0.125f;
    }
    __syncthreads();
    if (t < NPAT) {
        float m = ps[0];
        for (int n = 1; n < NPAT; ++n) m = fmaxf(m, ps[n]);
        float sum = 0.f;
        for (int n = 0; n < NPAT; ++n) sum += expf(ps[n] - m);
        float e = expf(ps[t] - m);
        out2[(size_t)row * NPAT + t] = e / sum * ldin(gate, t, f32);
    }
}

// ---------------------------------------------------------------------------
// K2: f32 projection (z=0:Q, 1:K, 2:V). EXACT-SENSITIVE (feeds mask top-k):
// each output element is one sequential f32 FMA chain over d ascending.
// DO NOT change numerics (validated round 8).
// ---------------------------------------------------------------------------
__global__ __launch_bounds__(256)
void projf_kernel(const void* __restrict__ query, const void* __restrict__ key,
                  const void* __restrict__ value,
                  const void* __restrict__ wq, const void* __restrict__ bq,
                  const void* __restrict__ wk, const void* __restrict__ bk,
                  const void* __restrict__ wv, const void* __restrict__ bv,
                  const int* __restrict__ flagp,
                  float* __restrict__ Qf32, float* __restrict__ Kf32, float* __restrict__ Vf32) {
    __shared__ float Xs[64][65];
    __shared__ float Ws[64][65];
    int f32 = *flagp;
    int z = blockIdx.z;
    const void* X = (z == 0) ? query : ((z == 1) ? key : value);
    const void* W = (z == 0) ? wq : ((z == 1) ? wk : wv);
    const void* Bv = (z == 0) ? bq : ((z == 1) ? bk : bv);
    float* Y = (z == 0) ? Qf32 : ((z == 1) ? Kf32 : Vf32);
    int c0 = blockIdx.x * 64, r0 = blockIdx.y * 64;
    int tx = threadIdx.x & 15, ty = threadIdx.x >> 4;
    float acc[4][4] = {};
    for (int k0 = 0; k0 < DDM; k0 += 64) {
        for (int idx = threadIdx.x; idx < 64 * 64; idx += 256) {
            int r = idx >> 6, kk = idx & 63;
            Xs[r][kk] = ldin(X, (size_t)(r0 + r) * DDM + k0 + kk, f32);
            Ws[r][kk] = ldin(W, (size_t)(k0 + r) * DDM + c0 + kk, f32);
        }
        __syncthreads();
        for (int kk = 0; kk < 64; ++kk) {           // ascending k: exact chain
            float xv[4], wv[4];
            #pragma unroll
            for (int a = 0; a < 4; ++a) xv[a] = Xs[ty + 16 * a][kk];
            #pragma unroll
            for (int b2 = 0; b2 < 4; ++b2) wv[b2] = Ws[kk][tx + 16 * b2];
            #pragma unroll
            for (int a = 0; a < 4; ++a)
                #pragma unroll
                for (int b2 = 0; b2 < 4; ++b2)
                    acc[a][b2] = fmaf(xv[a], wv[b2], acc[a][b2]);
        }
        __syncthreads();
    }
    #pragma unroll
    for (int a = 0; a < 4; ++a) {
        int r = r0 + ty + 16 * a;
        #pragma unroll
        for (int b2 = 0; b2 < 4; ++b2) {
            int c = c0 + tx + 16 * b2;
            Y[(size_t)r * DDM + c] = acc[a][b2] + ldin(Bv, c, f32);
        }
    }
}

// ---------------------------------------------------------------------------
// K3: f32 scores, all batches (z=batch). EXACT-SENSITIVE: sequential FMA
// chain over d ascending, then *0.125f. Numerics identical to round 8.
// ---------------------------------------------------------------------------
__global__ __launch_bounds__(256)
void scoresf_kernel(const float* __restrict__ Qf32, const float* __restrict__ Kf32,
                    float* __restrict__ S3f) {
    __shared__ float Qs[64][65];
    __shared__ float Ks[64][65];
    int b = blockIdx.z;
    const float* Qb = Qf32 + (size_t)b * SSQ * DDM;
    const float* Kb = Kf32 + (size_t)b * SSQ * DDM;
    float* S3 = S3f + (size_t)b * SSQ * SSQ;
    int j0 = blockIdx.x * 64, i0 = blockIdx.y * 64;
    int tx = threadIdx.x & 15, ty = threadIdx.x >> 4;
    float acc[4][4] = {};
    for (int k0 = 0; k0 < DDM; k0 += 64) {
        for (int idx = threadIdx.x; idx < 64 * 64; idx += 256) {
            int r = idx >> 6, kk = idx & 63;
            Qs[r][kk] = Qb[(size_t)(i0 + r) * DDM + k0 + kk];
            Ks[r][kk] = Kb[(size_t)(j0 + r) * DDM + k0 + kk];
        }
        __syncthreads();
        for (int kk = 0; kk < 64; ++kk) {           // ascending d: exact chain
            float qv[4], kv[4];
            #pragma unroll
            for (int a = 0; a < 4; ++a) qv[a] = Qs[ty + 16 * a][kk];
            #pragma unroll
            for (int b2 = 0; b2 < 4; ++b2) kv[b2] = Ks[tx + 16 * b2][kk];
            #pragma unroll
            for (int a = 0; a < 4; ++a)
                #pragma unroll
                for (int b2 = 0; b2 < 4; ++b2)
                    acc[a][b2] = fmaf(qv[a], kv[b2], acc[a][b2]);
        }
        __syncthreads();
    }
    #pragma unroll
    for (int a = 0; a < 4; ++a)
        #pragma unroll
        for (int b2 = 0; b2 < 4; ++b2)
            S3[(size_t)(i0 + ty + 16 * a) * SSQ + (j0 + tx + 16 * b2)] = acc[a][b2] * 0.125f;
}

// ---------------------------------------------------------------------------
// K4: per-row top-204 via 4-pass radix select on monotonic u32 keys.
// Exact integer logic; set semantics identical to iterated argmax
// (value desc, tie -> ascending index). blockIdx: x=row i, y=batch b.
// ---------------------------------------------------------------------------
__global__ __launch_bounds__(256)
void maskselect_kernel(const float* __restrict__ S3f,
                       u64* __restrict__ bitmask) {   // (B*S, 16)
    __shared__ u32 keys[1024];
    __shared__ u32 sel[1024];
    __shared__ u32 hist[256];
    __shared__ u32 ssum[256];
    __shared__ u32 scan[256];
    __shared__ u32 pick_digit, pick_rem;
    int i = blockIdx.x, b = blockIdx.y;
    int t = threadIdx.x;
    const float* srow = S3f + (size_t)b * SSQ * SSQ + (size_t)i * SSQ;
    for (int j = t; j < 1024; j += 256) {
        u32 bits = __float_as_uint(srow[j]);
        // monotonic map f32 -> u32 (total order, -0 < +0)
        keys[j] = (bits & 0x80000000u) ? ~bits : (bits | 0x80000000u);
    }
    __syncthreads();
    u32 prefix = 0, himask = 0, rem = KTOP;
    for (int p = 3; p >= 0; --p) {
        int shift = p * 8;
        hist[t] = 0;
        __syncthreads();
        for (int j = t; j < 1024; j += 256) {
            u32 kb = keys[j];
            if ((kb & himask) == prefix) atomicAdd(&hist[(kb >> shift) & 0xFFu], 1u);
        }
        __syncthreads();
        ssum[t] = hist[t];
        __syncthreads();
        for (int off = 1; off < 256; off <<= 1) {   // suffix sums
            u32 v = (t + off < 256) ? ssum[t + off] : 0u;
            __syncthreads();
            ssum[t] += v;
            __syncthreads();
        }
        u32 nxt = (t < 255) ? ssum[t + 1] : 0u;
        if (ssum[t] >= rem && nxt < rem) { pick_digit = (u32)t; pick_rem = rem - nxt; }
        __syncthreads();
        prefix |= pick_digit << shift;
        rem = pick_rem;
        himask |= (0xFFu << shift);
        __syncthreads();
    }
    u32 vstar = prefix;
    u32 tneed = rem;                 // how many == vstar to take, ascending index
    u32 eq[4]; u32 local = 0;
    #pragma unroll
    for (int a = 0; a < 4; ++a) {
        int j = 4 * t + a;
        u32 kb = keys[j];
        sel[j] = (kb > vstar) ? 1u : 0u;
        eq[a] = (kb == vstar) ? 1u : 0u;
        local += eq[a];
    }
    scan[t] = local;
    __syncthreads();
    for (int off = 1; off < 256; off <<= 1) {       // inclusive scan
        u32 v = (t >= off) ? scan[t - off] : 0u;
        __syncthreads();
        scan[t] += v;
        __syncthreads();
    }
    u32 base = (t > 0) ? scan[t - 1] : 0u;          // exclusive rank among equals
    #pragma unroll
    for (int a = 0; a < 4; ++a) {
        if (eq[a]) { if (base < tneed) sel[4 * t + a] = 1u; base += 1; }
    }
    __syncthreads();
    if (t < 16) {
        u64 wbits = 0;
        for (int l = 0; l < 64; ++l)
            if (sel[t * 64 + l]) wbits |= (1ull << l);
        bitmask[((size_t)b * SSQ + i) * 16 + t] = wbits;
    }
}

// ---------------------------------------------------------------------------
// K5: sparse attention. One wave per (b,h,i) row; gather 204 active columns
// from the bitmask (wave-uniform word reads), softmax over active set only
// (bitwise-equal to dense: masked terms contributed exactly 0), V-accum with
// 4 independent chains. Loose-tolerance path (out0 headroom ~100x).
// ---------------------------------------------------------------------------
__global__ __launch_bounds__(256)
void attn_sparse_kernel(const float* __restrict__ Qf32, const float* __restrict__ Kf32,
                        const float* __restrict__ Vf32, const u64* __restrict__ bitmask,
                        float* __restrict__ AO) {
    __shared__ float qs[4][64];
    __shared__ float pbuf[4][256];
    __shared__ u16 list[4][256];
    int lane = threadIdx.x & 63, w = threadIdx.x >> 6;
    int b = blockIdx.z, h = blockIdx.y, i = blockIdx.x * 4 + w;
    size_t qoff = ((size_t)(b * SSQ + i)) * DDM + h * 64;
    qs[w][lane] = Qf32[qoff + lane];
    const u64* mb = bitmask + ((size_t)(b * SSQ + i)) * 16;
    u64 below = (lane == 0) ? 0ull : (0xFFFFFFFFFFFFFFFFull >> (64 - lane));
    int cnt = 0;
    #pragma unroll
    for (int wd = 0; wd < 16; ++wd) {
        u64 word = mb[wd];                       // wave-uniform
        if ((word >> lane) & 1ull) {
            int pos = cnt + (int)__popcll(word & below);
            if (pos < 256) list[w][pos] = (u16)(wd * 64 + lane);
        }
        cnt += (int)__popcll(word);
    }
    if (cnt > 256) cnt = 256;
    // scores over active columns (lane = list index)
    float sv[4];
    float m = -1e30f;
    const float* Kb = Kf32 + (size_t)b * SSQ * DDM + h * 64;
    #pragma unroll
    for (int c = 0; c < 4; ++c) {
        int idx = c * 64 + lane;
        float s = -1e30f;
        if (idx < cnt) {
            int j = list[w][idx];
            const float* kr = Kb + (size_t)j * DDM;
            float acc = 0.f;
            #pragma unroll
            for (int d = 0; d < 64; d += 4) {
                float4 kv = *reinterpret_cast<const float4*>(kr + d);
                acc += qs[w][d] * kv.x + qs[w][d + 1] * kv.y +
                       qs[w][d + 2] * kv.z + qs[w][d + 3] * kv.w;
            }
            s = acc * 0.125f;
        }
        sv[c] = s;
        m = fmaxf(m, s);
    }
    #pragma unroll
    for (int off = 32; off >= 1; off >>= 1) m = fmaxf(m, __shfl_xor(m, off));
    float lsum = 0.f;
    #pragma unroll
    for (int c = 0; c < 4; ++c) {
        int idx = c * 64 + lane;
        if (idx < cnt) {
            float p = expf(sv[c] - m);
            pbuf[w][idx] = p;
            lsum += p;
        }
    }
    #pragma unroll
    for (int off = 32; off >= 1; off >>= 1) lsum += __shfl_xor(lsum, off);
    // V accumulation: lane = d, 4 independent chains over the active list
    const float* Vb = Vf32 + (size_t)b * SSQ * DDM + h * 64 + lane;
    float a0 = 0.f, a1 = 0.f, a2 = 0.f, a3 = 0.f;
    int tt = 0;
    for (; tt + 4 <= cnt; tt += 4) {
        a0 = fmaf(pbuf[w][tt + 0], Vb[(size_t)list[w][tt + 0] * DDM], a0);
        a1 = fmaf(pbuf[w][tt + 1], Vb[(size_t)list[w][tt + 1] * DDM], a1);
        a2 = fmaf(pbuf[w][tt + 2], Vb[(size_t)list[w][tt + 2] * DDM], a2);
        a3 = fmaf(pbuf[w][tt + 3], Vb[(size_t)list[w][tt + 3] * DDM], a3);
    }
    for (; tt < cnt; ++tt) a0 = fmaf(pbuf[w][tt], Vb[(size_t)list[w][tt] * DDM], a0);
    AO[qoff + lane] = ((a0 + a1) + (a2 + a3)) / lsum;
}

// ---------------------------------------------------------------------------
// K6: output projection  out0 = AO @ wo + bo  (f32 out)
// ---------------------------------------------------------------------------
__global__ __launch_bounds__(256)
void outproj_kernel(const float* __restrict__ AO, const void* __restrict__ wo,
                    const void* __restrict__ bo, const int* __restrict__ flagp,
                    float* __restrict__ out0) {
    __shared__ float Xs[64][65];
    __shared__ float Ws[64][65];
    int f32 = *flagp;
    int c0 = blockIdx.x * 64, r0 = blockIdx.y * 64;
    int tx = threadIdx.x & 15, ty = threadIdx.x >> 4;
    float acc[4][4] = {};
    for (int k0 = 0; k0 < DDM; k0 += 64) {
        for (int idx = threadIdx.x; idx < 64 * 64; idx += 256) {
            int r = idx >> 6, kk = idx & 63;
            Xs[r][kk] = AO[(size_t)(r0 + r) * DDM + k0 + kk];
            Ws[r][kk] = ldin(wo, (size_t)(k0 + r) * DDM + c0 + kk, f32);
        }
        __syncthreads();
        for (int kk = 0; kk < 64; ++kk) {
            float xv[4], wv[4];
            #pragma unroll
            for (int a = 0; a < 4; ++a) xv[a] = Xs[ty + 16 * a][kk];
            #pragma unroll
            for (int b2 = 0; b2 < 4; ++b2) wv[b2] = Ws[kk][tx + 16 * b2];
            #pragma unroll
            for (int a = 0; a < 4; ++a)
                #pragma unroll
                for (int b2 = 0; b2 < 4; ++b2)
                    acc[a][b2] = fmaf(xv[a], wv[b2], acc[a][b2]);
        }
        __syncthreads();
    }
    #pragma unroll
    for (int a = 0; a < 4; ++a) {
        int r = r0 + ty + 16 * a;
        #pragma unroll
        for (int b2 = 0; b2 < 4; ++b2) {
            int c = c0 + tx + 16 * b2;
            out0[(size_t)r * DDM + c] = acc[a][b2] + ldin(bo, c, f32);
        }
    }
}

// ---------------------------------------------------------------------------
// K7 (last): expand bitmask -> f32 mask for all 8 heads, overwriting ALL of
// out1 (which served as scratch until now). One block per (b,i) row.
// ---------------------------------------------------------------------------
__global__ __launch_bounds__(256)
void maskwrite_kernel(const u64* __restrict__ bitmask,
                      float* __restrict__ out1) {
    int row = blockIdx.x;            // b*S + i
    int t = threadIdx.x;
    int b = row >> 10, i = row & 1023;
    const u64* mb = bitmask + (size_t)row * 16;
    int j0 = t * 4;
    u64 w0 = mb[j0 >> 6];
    float4 v4;
    v4.x = ((w0 >> (j0 & 63)) & 1ull) ? 1.0f : 0.0f;
    v4.y = ((w0 >> ((j0 + 1) & 63)) & 1ull) ? 1.0f : 0.0f;
    v4.z = ((w0 >> ((j0 + 2) & 63)) & 1ull) ? 1.0f : 0.0f;
    v4.w = ((w0 >> ((j0 + 3) & 63)) & 1ull) ? 1.0f : 0.0f;
    for (int h = 0; h < HHD; ++h) {
        size_t base_o = (((size_t)b * HHD + h) * SSQ + i) * SSQ;
        *reinterpret_cast<float4*>(out1 + base_o + (size_t)t * 4) = v4;
    }
}

// ---------------------------------------------------------------------------
extern "C" void kernel_launch(void* const* d_in, const int* in_sizes, int n_in,
                              void* d_out, int out_size, void* d_ws, size_t ws_size,
                              hipStream_t stream) {
    const void* query = d_in[0];
    const void* key   = d_in[1];
    const void* value = d_in[2];
    const void* wq = d_in[3];  const void* bq = d_in[4];
    const void* wk = d_in[5];  const void* bk = d_in[6];
    const void* wv = d_in[7];  const void* bv = d_in[8];
    const void* wo = d_in[9];  const void* bo = d_in[10];
    const void* pw1 = d_in[11]; const void* pb1 = d_in[12];
    const void* pw2 = d_in[13]; const void* pb2 = d_in[14];
    const void* pattern_bank = d_in[15];
    const void* pattern_gate = d_in[16];

    // Outputs are FLOAT32 (validated round 8).
    float* out0 = (float*)d_out;                          // (B,S,D)   2M f32
    float* out1 = out0 + (size_t)BB * SSQ * DDM;          // (B,H,S,S) 33.5M f32 (134MB)
    float* out2 = out1 + (size_t)BB * HHD * SSQ * SSQ;    // (B,S,NP)  32K f32

    // d_ws: tiny header only (dtype flag + 512KB bitmask).
    int* flag = (int*)d_ws;
    u64* bitmask = (u64*)((char*)d_ws + 65536);           // (B*S,16) = 512KB

    // All large scratch lives INSIDE out1's 134MB, overwritten by maskwrite.
    char* SCR = (char*)out1;
    float* Qf32 = (float*)(SCR);                          // [0,8M)
    float* Kf32 = (float*)(SCR + (8ull << 20));           // [8M,16M)
    float* Vf32 = (float*)(SCR + (16ull << 20));          // [16M,24M)
    float* AO   = (float*)(SCR + (24ull << 20));          // [24M,32M)
    float* S3f  = (float*)(SCR + (32ull << 20));          // [32M,48M) all-batch scores

    detect_kernel<<<dim3(1), dim3(64), 0, stream>>>(query, flag);

    pattern_kernel<<<dim3(BB * SSQ), dim3(64), 0, stream>>>(
        query, pw1, pb1, pw2, pb2, pattern_bank, pattern_gate, flag, out2);

    // f32 Q/K/V projections (exact sequential-FMA-chain semantics)
    projf_kernel<<<dim3(DDM / 64, BB * SSQ / 64, 3), dim3(256), 0, stream>>>(
        query, key, value, wq, bq, wk, bk, wv, bv, flag, Qf32, Kf32, Vf32);

    // f32 scores, all batches in one launch (4x occupancy vs per-batch)
    scoresf_kernel<<<dim3(SSQ / 64, SSQ / 64, BB), dim3(256), 0, stream>>>(
        Qf32, Kf32, S3f);

    // top-204 per row, all batches, radix select
    maskselect_kernel<<<dim3(SSQ, BB), dim3(256), 0, stream>>>(S3f, bitmask);

    // sparse attention over the 204 active columns
    attn_sparse_kernel<<<dim3(SSQ / 4, HHD, BB), dim3(256), 0, stream>>>(
        Qf32, Kf32, Vf32, bitmask, AO);

    outproj_kernel<<<dim3(DDM / 64, BB * SSQ / 64), dim3(256), 0, stream>>>(
        AO, wo, bo, flag, out0);

    // LAST: expand bitmask into out1 (f32 mask), erasing all scratch
    maskwrite_kernel<<<dim3(BB * SSQ), dim3(256), 0, stream>>>(bitmask, out1);
}

// Round 10
// 953.906 us; speedup vs baseline: 3.3092x; 1.0556x over previous
//
#include <hip/hip_runtime.h>
#include <hip/hip_bf16.h>
#include <math.h>

// Problem constants
#define BB   4
#define SSQ  1024
#define DDM  512
#define HHD  8
#define KTOP 204
#define NPAT 8
#define PDIM 64

typedef unsigned long long u64;
typedef unsigned int u32;
typedef unsigned short u16;

// Polymorphic input loader: flag==1 -> f32 data, flag==0 -> bf16 data.
__device__ __forceinline__ float ldin(const void* p, size_t i, int f32) {
    if (f32) return ((const float*)p)[i];
    u16 h = ((const u16*)p)[i];
    return __uint_as_float(((u32)h) << 16);
}

// ---------------------------------------------------------------------------
// K0: input dtype detection (same sample set/decision as validated round 8,
// parallelized across 64 lanes).
// ---------------------------------------------------------------------------
__global__ __launch_bounds__(64)
void detect_kernel(const void* q, int* flag) {
    int lane = threadIdx.x;
    const u16* p = (const u16*)q;
    int good = 0;
    #pragma unroll
    for (int k = 0; k < 4; ++k) {
        int i = (lane * 4 + k) * 2;
        float v = __uint_as_float(((u32)p[i]) << 16);
        float a = fabsf(v);
        if (a > 0.00390625f && a < 64.f) ++good;
    }
    #pragma unroll
    for (int off = 32; off >= 1; off >>= 1) good += __shfl_xor(good, off);
    if (lane == 0) *flag = (good < 128) ? 1 : 0;
}

// ---------------------------------------------------------------------------
// K1: pattern learner -> weighted_patterns (out2, f32). One block per row.
// (loose tolerance: 4-partial chains OK)
// ---------------------------------------------------------------------------
__global__ __launch_bounds__(64)
void pattern_kernel(const void* __restrict__ q,
                    const void* __restrict__ pw1, const void* __restrict__ pb1,
                    const void* __restrict__ pw2, const void* __restrict__ pb2,
                    const void* __restrict__ bank, const void* __restrict__ gate,
                    const int* __restrict__ flagp,
                    float* __restrict__ out2) {
    __shared__ float qs[DDM];
    __shared__ float h1[PDIM];
    __shared__ float enc[PDIM];
    __shared__ float ps[NPAT];
    int f32 = *flagp;
    int row = blockIdx.x;
    int t = threadIdx.x;
    for (int i = t; i < DDM; i += 64) qs[i] = ldin(q, (size_t)row * DDM + i, f32);
    __syncthreads();
    float a0 = ldin(pb1, t, f32), a1 = 0.f, a2 = 0.f, a3 = 0.f;
    #pragma unroll 4
    for (int d = 0; d < DDM; d += 4) {
        a0 = fmaf(qs[d + 0], ldin(pw1, (size_t)(d + 0) * PDIM + t, f32), a0);
        a1 = fmaf(qs[d + 1], ldin(pw1, (size_t)(d + 1) * PDIM + t, f32), a1);
        a2 = fmaf(qs[d + 2], ldin(pw1, (size_t)(d + 2) * PDIM + t, f32), a2);
        a3 = fmaf(qs[d + 3], ldin(pw1, (size_t)(d + 3) * PDIM + t, f32), a3);
    }
    h1[t] = fmaxf((a0 + a1) + (a2 + a3), 0.f);
    __syncthreads();
    float acc2 = ldin(pb2, t, f32);
    for (int d = 0; d < PDIM; ++d) acc2 = fmaf(h1[d], ldin(pw2, (size_t)d * PDIM + t, f32), acc2);
    enc[t] = tanhf(acc2);
    __syncthreads();
    if (t < NPAT) {
        float a = 0.f;
        for (int d = 0; d < PDIM; ++d) a = fmaf(enc[d], ldin(bank, (size_t)t * PDIM + d, f32), a);
        ps[t] = a * 0.125f;
    }
    __syncthreads();
    if (t < NPAT) {
        float m = ps[0];
        for (int n = 1; n < NPAT; ++n) m = fmaxf(m, ps[n]);
        float sum = 0.f;
        for (int n = 0; n < NPAT; ++n) sum += expf(ps[n] - m);
        float e = expf(ps[t] - m);
        out2[(size_t)row * NPAT + t] = e / sum * ldin(gate, t, f32);
    }
}

// ---------------------------------------------------------------------------
// K2: f32 projection (z=0:Q, 1:K, 2:V). EXACT-SENSITIVE (feeds mask top-k):
// each output element is one sequential f32 FMA chain over d ascending —
// chain order identical to validated round 8 (vectorization only changes
// which thread computes which element / how operands are fetched).
// Thread (tx,ty) computes rows {ty+16a}, cols {c0+4tx+j}.
// ---------------------------------------------------------------------------
__global__ __launch_bounds__(256)
void projf_kernel(const void* __restrict__ query, const void* __restrict__ key,
                  const void* __restrict__ value,
                  const void* __restrict__ wq, const void* __restrict__ bq,
                  const void* __restrict__ wk, const void* __restrict__ bk,
                  const void* __restrict__ wv, const void* __restrict__ bv,
                  const int* __restrict__ flagp,
                  float* __restrict__ Qf32, float* __restrict__ Kf32, float* __restrict__ Vf32) {
    __shared__ float Xs[64][68];
    __shared__ float Ws[64][68];
    int f32 = *flagp;
    int z = blockIdx.z;
    const void* X = (z == 0) ? query : ((z == 1) ? key : value);
    const void* W = (z == 0) ? wq : ((z == 1) ? wk : wv);
    const void* Bv = (z == 0) ? bq : ((z == 1) ? bk : bv);
    float* Y = (z == 0) ? Qf32 : ((z == 1) ? Kf32 : Vf32);
    int c0 = blockIdx.x * 64, r0 = blockIdx.y * 64;
    int tx = threadIdx.x & 15, ty = threadIdx.x >> 4;
    float acc[4][4] = {};
    for (int k0 = 0; k0 < DDM; k0 += 64) {
        for (int idx = threadIdx.x; idx < 64 * 64; idx += 256) {
            int r = idx >> 6, kk = idx & 63;
            Xs[r][kk] = ldin(X, (size_t)(r0 + r) * DDM + k0 + kk, f32);
            Ws[r][kk] = ldin(W, (size_t)(k0 + r) * DDM + c0 + kk, f32);
        }
        __syncthreads();
        #pragma unroll 4
        for (int kk = 0; kk < 64; kk += 4) {
            float4 xv[4];
            #pragma unroll
            for (int a = 0; a < 4; ++a)
                xv[a] = *reinterpret_cast<const float4*>(&Xs[ty + 16 * a][kk]);
            #pragma unroll
            for (int j = 0; j < 4; ++j) {          // sub-k ascending: exact chain
                float4 wv = *reinterpret_cast<const float4*>(&Ws[kk + j][4 * tx]);
                #pragma unroll
                for (int a = 0; a < 4; ++a) {
                    float x = ((const float*)&xv[a])[j];
                    acc[a][0] = fmaf(x, wv.x, acc[a][0]);
                    acc[a][1] = fmaf(x, wv.y, acc[a][1]);
                    acc[a][2] = fmaf(x, wv.z, acc[a][2]);
                    acc[a][3] = fmaf(x, wv.w, acc[a][3]);
                }
            }
        }
        __syncthreads();
    }
    #pragma unroll
    for (int a = 0; a < 4; ++a) {
        int r = r0 + ty + 16 * a;
        float4 o;
        o.x = acc[a][0] + ldin(Bv, c0 + 4 * tx + 0, f32);
        o.y = acc[a][1] + ldin(Bv, c0 + 4 * tx + 1, f32);
        o.z = acc[a][2] + ldin(Bv, c0 + 4 * tx + 2, f32);
        o.w = acc[a][3] + ldin(Bv, c0 + 4 * tx + 3, f32);
        *reinterpret_cast<float4*>(&Y[(size_t)r * DDM + c0 + 4 * tx]) = o;
    }
}

// ---------------------------------------------------------------------------
// K3: f32 scores, all batches (z=batch). EXACT-SENSITIVE: sequential FMA
// chain over d ascending, then *0.125f. Chain order identical to round 8.
// ---------------------------------------------------------------------------
__global__ __launch_bounds__(256)
void scoresf_kernel(const float* __restrict__ Qf32, const float* __restrict__ Kf32,
                    float* __restrict__ S3f) {
    __shared__ float Qs[64][68];
    __shared__ float Ks[64][68];
    int b = blockIdx.z;
    const float* Qb = Qf32 + (size_t)b * SSQ * DDM;
    const float* Kb = Kf32 + (size_t)b * SSQ * DDM;
    float* S3 = S3f + (size_t)b * SSQ * SSQ;
    int j0 = blockIdx.x * 64, i0 = blockIdx.y * 64;
    int tx = threadIdx.x & 15, ty = threadIdx.x >> 4;
    float acc[4][4] = {};
    for (int k0 = 0; k0 < DDM; k0 += 64) {
        for (int idx = threadIdx.x; idx < 64 * 64; idx += 256) {
            int r = idx >> 6, kk = idx & 63;
            Qs[r][kk] = Qb[(size_t)(i0 + r) * DDM + k0 + kk];
            Ks[r][kk] = Kb[(size_t)(j0 + r) * DDM + k0 + kk];
        }
        __syncthreads();
        #pragma unroll 4
        for (int kk = 0; kk < 64; kk += 4) {
            float4 qv[4], kv[4];
            #pragma unroll
            for (int a = 0; a < 4; ++a)
                qv[a] = *reinterpret_cast<const float4*>(&Qs[ty + 16 * a][kk]);
            #pragma unroll
            for (int b2 = 0; b2 < 4; ++b2)
                kv[b2] = *reinterpret_cast<const float4*>(&Ks[tx + 16 * b2][kk]);
            #pragma unroll
            for (int a = 0; a < 4; ++a)
                #pragma unroll
                for (int b2 = 0; b2 < 4; ++b2) {   // .x,.y,.z,.w ascending: exact
                    acc[a][b2] = fmaf(qv[a].x, kv[b2].x, acc[a][b2]);
                    acc[a][b2] = fmaf(qv[a].y, kv[b2].y, acc[a][b2]);
                    acc[a][b2] = fmaf(qv[a].z, kv[b2].z, acc[a][b2]);
                    acc[a][b2] = fmaf(qv[a].w, kv[b2].w, acc[a][b2]);
                }
        }
        __syncthreads();
    }
    #pragma unroll
    for (int a = 0; a < 4; ++a)
        #pragma unroll
        for (int b2 = 0; b2 < 4; ++b2)
            S3[(size_t)(i0 + ty + 16 * a) * SSQ + (j0 + tx + 16 * b2)] = acc[a][b2] * 0.125f;
}

// ---------------------------------------------------------------------------
// K4: per-row top-204 via 4-pass radix select on monotonic u32 keys.
// VALIDATED round 9 — unchanged.
// ---------------------------------------------------------------------------
__global__ __launch_bounds__(256)
void maskselect_kernel(const float* __restrict__ S3f,
                       u64* __restrict__ bitmask) {   // (B*S, 16)
    __shared__ u32 keys[1024];
    __shared__ u32 sel[1024];
    __shared__ u32 hist[256];
    __shared__ u32 ssum[256];
    __shared__ u32 scan[256];
    __shared__ u32 pick_digit, pick_rem;
    int i = blockIdx.x, b = blockIdx.y;
    int t = threadIdx.x;
    const float* srow = S3f + (size_t)b * SSQ * SSQ + (size_t)i * SSQ;
    for (int j = t; j < 1024; j += 256) {
        u32 bits = __float_as_uint(srow[j]);
        keys[j] = (bits & 0x80000000u) ? ~bits : (bits | 0x80000000u);
    }
    __syncthreads();
    u32 prefix = 0, himask = 0, rem = KTOP;
    for (int p = 3; p >= 0; --p) {
        int shift = p * 8;
        hist[t] = 0;
        __syncthreads();
        for (int j = t; j < 1024; j += 256) {
            u32 kb = keys[j];
            if ((kb & himask) == prefix) atomicAdd(&hist[(kb >> shift) & 0xFFu], 1u);
        }
        __syncthreads();
        ssum[t] = hist[t];
        __syncthreads();
        for (int off = 1; off < 256; off <<= 1) {
            u32 v = (t + off < 256) ? ssum[t + off] : 0u;
            __syncthreads();
            ssum[t] += v;
            __syncthreads();
        }
        u32 nxt = (t < 255) ? ssum[t + 1] : 0u;
        if (ssum[t] >= rem && nxt < rem) { pick_digit = (u32)t; pick_rem = rem - nxt; }
        __syncthreads();
        prefix |= pick_digit << shift;
        rem = pick_rem;
        himask |= (0xFFu << shift);
        __syncthreads();
    }
    u32 vstar = prefix;
    u32 tneed = rem;
    u32 eq[4]; u32 local = 0;
    #pragma unroll
    for (int a = 0; a < 4; ++a) {
        int j = 4 * t + a;
        u32 kb = keys[j];
        sel[j] = (kb > vstar) ? 1u : 0u;
        eq[a] = (kb == vstar) ? 1u : 0u;
        local += eq[a];
    }
    scan[t] = local;
    __syncthreads();
    for (int off = 1; off < 256; off <<= 1) {
        u32 v = (t >= off) ? scan[t - off] : 0u;
        __syncthreads();
        scan[t] += v;
        __syncthreads();
    }
    u32 base = (t > 0) ? scan[t - 1] : 0u;
    #pragma unroll
    for (int a = 0; a < 4; ++a) {
        if (eq[a]) { if (base < tneed) sel[4 * t + a] = 1u; base += 1; }
    }
    __syncthreads();
    if (t < 16) {
        u64 wbits = 0;
        for (int l = 0; l < 64; ++l)
            if (sel[t * 64 + l]) wbits |= (1ull << l);
        bitmask[((size_t)b * SSQ + i) * 16 + t] = wbits;
    }
}

// ---------------------------------------------------------------------------
// K5: sparse attention. One wave per (b,h,i) row. Loose-tolerance path:
// 4-partial K-dot (chain 16 deep), float4 q/k loads, V-accum 4 chains
// unrolled 2x (8 loads in flight).
// ---------------------------------------------------------------------------
__global__ __launch_bounds__(256)
void attn_sparse_kernel(const float* __restrict__ Qf32, const float* __restrict__ Kf32,
                        const float* __restrict__ Vf32, const u64* __restrict__ bitmask,
                        float* __restrict__ AO) {
    __shared__ float qs[4][64];
    __shared__ float pbuf[4][256];
    __shared__ u16 list[4][256];
    int lane = threadIdx.x & 63, w = threadIdx.x >> 6;
    int b = blockIdx.z, h = blockIdx.y, i = blockIdx.x * 4 + w;
    size_t qoff = ((size_t)(b * SSQ + i)) * DDM + h * 64;
    qs[w][lane] = Qf32[qoff + lane];
    const u64* mb = bitmask + ((size_t)(b * SSQ + i)) * 16;
    u64 below = (lane == 0) ? 0ull : (0xFFFFFFFFFFFFFFFFull >> (64 - lane));
    int cnt = 0;
    #pragma unroll
    for (int wd = 0; wd < 16; ++wd) {
        u64 word = mb[wd];                       // wave-uniform
        if ((word >> lane) & 1ull) {
            int pos = cnt + (int)__popcll(word & below);
            if (pos < 256) list[w][pos] = (u16)(wd * 64 + lane);
        }
        cnt += (int)__popcll(word);
    }
    if (cnt > 256) cnt = 256;
    float sv[4];
    float m = -1e30f;
    const float* Kb = Kf32 + (size_t)b * SSQ * DDM + h * 64;
    #pragma unroll
    for (int c = 0; c < 4; ++c) {
        int idx = c * 64 + lane;
        float s = -1e30f;
        if (idx < cnt) {
            int j = list[w][idx];
            const float* kr = Kb + (size_t)j * DDM;
            float p0 = 0.f, p1 = 0.f, p2 = 0.f, p3 = 0.f;
            #pragma unroll
            for (int d = 0; d < 64; d += 16) {
                float4 q0 = *reinterpret_cast<const float4*>(&qs[w][d]);
                float4 q1 = *reinterpret_cast<const float4*>(&qs[w][d + 4]);
                float4 q2 = *reinterpret_cast<const float4*>(&qs[w][d + 8]);
                float4 q3 = *reinterpret_cast<const float4*>(&qs[w][d + 12]);
                float4 k0 = *reinterpret_cast<const float4*>(kr + d);
                float4 k1 = *reinterpret_cast<const float4*>(kr + d + 4);
                float4 k2 = *reinterpret_cast<const float4*>(kr + d + 8);
                float4 k3 = *reinterpret_cast<const float4*>(kr + d + 12);
                p0 = fmaf(q0.w, k0.w, fmaf(q0.z, k0.z, fmaf(q0.y, k0.y, fmaf(q0.x, k0.x, p0))));
                p1 = fmaf(q1.w, k1.w, fmaf(q1.z, k1.z, fmaf(q1.y, k1.y, fmaf(q1.x, k1.x, p1))));
                p2 = fmaf(q2.w, k2.w, fmaf(q2.z, k2.z, fmaf(q2.y, k2.y, fmaf(q2.x, k2.x, p2))));
                p3 = fmaf(q3.w, k3.w, fmaf(q3.z, k3.z, fmaf(q3.y, k3.y, fmaf(q3.x, k3.x, p3))));
            }
            s = ((p0 + p1) + (p2 + p3)) * 0.125f;
        }
        sv[c] = s;
        m = fmaxf(m, s);
    }
    #pragma unroll
    for (int off = 32; off >= 1; off >>= 1) m = fmaxf(m, __shfl_xor(m, off));
    float lsum = 0.f;
    #pragma unroll
    for (int c = 0; c < 4; ++c) {
        int idx = c * 64 + lane;
        if (idx < cnt) {
            float p = expf(sv[c] - m);
            pbuf[w][idx] = p;
            lsum += p;
        }
    }
    #pragma unroll
    for (int off = 32; off >= 1; off >>= 1) lsum += __shfl_xor(lsum, off);
    const float* Vb = Vf32 + (size_t)b * SSQ * DDM + h * 64 + lane;
    float a0 = 0.f, a1 = 0.f, a2 = 0.f, a3 = 0.f;
    int tt = 0;
    #pragma unroll 2
    for (; tt + 4 <= cnt; tt += 4) {
        a0 = fmaf(pbuf[w][tt + 0], Vb[(size_t)list[w][tt + 0] * DDM], a0);
        a1 = fmaf(pbuf[w][tt + 1], Vb[(size_t)list[w][tt + 1] * DDM], a1);
        a2 = fmaf(pbuf[w][tt + 2], Vb[(size_t)list[w][tt + 2] * DDM], a2);
        a3 = fmaf(pbuf[w][tt + 3], Vb[(size_t)list[w][tt + 3] * DDM], a3);
    }
    for (; tt < cnt; ++tt) a0 = fmaf(pbuf[w][tt], Vb[(size_t)list[w][tt] * DDM], a0);
    AO[qoff + lane] = ((a0 + a1) + (a2 + a3)) / lsum;
}

// ---------------------------------------------------------------------------
// K6: output projection  out0 = AO @ wo + bo  (f32 out, loose tolerance)
// ---------------------------------------------------------------------------
__global__ __launch_bounds__(256)
void outproj_kernel(const float* __restrict__ AO, const void* __restrict__ wo,
                    const void* __restrict__ bo, const int* __restrict__ flagp,
                    float* __restrict__ out0) {
    __shared__ float Xs[64][68];
    __shared__ float Ws[64][68];
    int f32 = *flagp;
    int c0 = blockIdx.x * 64, r0 = blockIdx.y * 64;
    int tx = threadIdx.x & 15, ty = threadIdx.x >> 4;
    float acc[4][4] = {};
    for (int k0 = 0; k0 < DDM; k0 += 64) {
        for (int idx = threadIdx.x; idx < 64 * 64; idx += 256) {
            int r = idx >> 6, kk = idx & 63;
            Xs[r][kk] = AO[(size_t)(r0 + r) * DDM + k0 + kk];
            Ws[r][kk] = ldin(wo, (size_t)(k0 + r) * DDM + c0 + kk, f32);
        }
        __syncthreads();
        #pragma unroll 4
        for (int kk = 0; kk < 64; kk += 4) {
            float4 xv[4];
            #pragma unroll
            for (int a = 0; a < 4; ++a)
                xv[a] = *reinterpret_cast<const float4*>(&Xs[ty + 16 * a][kk]);
            #pragma unroll
            for (int j = 0; j < 4; ++j) {
                float4 wv = *reinterpret_cast<const float4*>(&Ws[kk + j][4 * tx]);
                #pragma unroll
                for (int a = 0; a < 4; ++a) {
                    float x = ((const float*)&xv[a])[j];
                    acc[a][0] = fmaf(x, wv.x, acc[a][0]);
                    acc[a][1] = fmaf(x, wv.y, acc[a][1]);
                    acc[a][2] = fmaf(x, wv.z, acc[a][2]);
                    acc[a][3] = fmaf(x, wv.w, acc[a][3]);
                }
            }
        }
        __syncthreads();
    }
    #pragma unroll
    for (int a = 0; a < 4; ++a) {
        int r = r0 + ty + 16 * a;
        float4 o;
        o.x = acc[a][0] + ldin(bo, c0 + 4 * tx + 0, f32);
        o.y = acc[a][1] + ldin(bo, c0 + 4 * tx + 1, f32);
        o.z = acc[a][2] + ldin(bo, c0 + 4 * tx + 2, f32);
        o.w = acc[a][3] + ldin(bo, c0 + 4 * tx + 3, f32);
        *reinterpret_cast<float4*>(&out0[(size_t)r * DDM + c0 + 4 * tx]) = o;
    }
}

// ---------------------------------------------------------------------------
// K7 (last): expand bitmask -> f32 mask for all 8 heads, overwriting ALL of
// out1 (which served as scratch until now). One block per (b,i) row.
// ---------------------------------------------------------------------------
__global__ __launch_bounds__(256)
void maskwrite_kernel(const u64* __restrict__ bitmask,
                      float* __restrict__ out1) {
    int row = blockIdx.x;            // b*S + i
    int t = threadIdx.x;
    int b = row >> 10, i = row & 1023;
    const u64* mb = bitmask + (size_t)row * 16;
    int j0 = t * 4;
    u64 w0 = mb[j0 >> 6];
    float4 v4;
    v4.x = ((w0 >> (j0 & 63)) & 1ull) ? 1.0f : 0.0f;
    v4.y = ((w0 >> ((j0 + 1) & 63)) & 1ull) ? 1.0f : 0.0f;
    v4.z = ((w0 >> ((j0 + 2) & 63)) & 1ull) ? 1.0f : 0.0f;
    v4.w = ((w0 >> ((j0 + 3) & 63)) & 1ull) ? 1.0f : 0.0f;
    for (int h = 0; h < HHD; ++h) {
        size_t base_o = (((size_t)b * HHD + h) * SSQ + i) * SSQ;
        *reinterpret_cast<float4*>(out1 + base_o + (size_t)t * 4) = v4;
    }
}

// ---------------------------------------------------------------------------
extern "C" void kernel_launch(void* const* d_in, const int* in_sizes, int n_in,
                              void* d_out, int out_size, void* d_ws, size_t ws_size,
                              hipStream_t stream) {
    const void* query = d_in[0];
    const void* key   = d_in[1];
    const void* value = d_in[2];
    const void* wq = d_in[3];  const void* bq = d_in[4];
    const void* wk = d_in[5];  const void* bk = d_in[6];
    const void* wv = d_in[7];  const void* bv = d_in[8];
    const void* wo = d_in[9];  const void* bo = d_in[10];
    const void* pw1 = d_in[11]; const void* pb1 = d_in[12];
    const void* pw2 = d_in[13]; const void* pb2 = d_in[14];
    const void* pattern_bank = d_in[15];
    const void* pattern_gate = d_in[16];

    // Outputs are FLOAT32 (validated round 8).
    float* out0 = (float*)d_out;                          // (B,S,D)   2M f32
    float* out1 = out0 + (size_t)BB * SSQ * DDM;          // (B,H,S,S) 33.5M f32 (134MB)
    float* out2 = out1 + (size_t)BB * HHD * SSQ * SSQ;    // (B,S,NP)  32K f32

    // d_ws: tiny header only (dtype flag + 512KB bitmask).
    int* flag = (int*)d_ws;
    u64* bitmask = (u64*)((char*)d_ws + 65536);           // (B*S,16) = 512KB

    // All large scratch lives INSIDE out1's 134MB, overwritten by maskwrite.
    char* SCR = (char*)out1;
    float* Qf32 = (float*)(SCR);                          // [0,8M)
    float* Kf32 = (float*)(SCR + (8ull << 20));           // [8M,16M)
    float* Vf32 = (float*)(SCR + (16ull << 20));          // [16M,24M)
    float* AO   = (float*)(SCR + (24ull << 20));          // [24M,32M)
    float* S3f  = (float*)(SCR + (32ull << 20));          // [32M,48M) all-batch scores

    detect_kernel<<<dim3(1), dim3(64), 0, stream>>>(query, flag);

    pattern_kernel<<<dim3(BB * SSQ), dim3(64), 0, stream>>>(
        query, pw1, pb1, pw2, pb2, pattern_bank, pattern_gate, flag, out2);

    // f32 Q/K/V projections (exact sequential-FMA-chain semantics)
    projf_kernel<<<dim3(DDM / 64, BB * SSQ / 64, 3), dim3(256), 0, stream>>>(
        query, key, value, wq, bq, wk, bk, wv, bv, flag, Qf32, Kf32, Vf32);

    // f32 scores, all batches in one launch
    scoresf_kernel<<<dim3(SSQ / 64, SSQ / 64, BB), dim3(256), 0, stream>>>(
        Qf32, Kf32, S3f);

    // top-204 per row, all batches, radix select (validated)
    maskselect_kernel<<<dim3(SSQ, BB), dim3(256), 0, stream>>>(S3f, bitmask);

    // sparse attention over the 204 active columns
    attn_sparse_kernel<<<dim3(SSQ / 4, HHD, BB), dim3(256), 0, stream>>>(
        Qf32, Kf32, Vf32, bitmask, AO);

    outproj_kernel<<<dim3(DDM / 64, BB * SSQ / 64), dim3(256), 0, stream>>>(
        AO, wo, bo, flag, out0);

    // LAST: expand bitmask into out1 (f32 mask), erasing all scratch
    maskwrite_kernel<<<dim3(BB * SSQ), dim3(256), 0, stream>>>(bitmask, out1);
}